// Round 11
// baseline (181.888 us; speedup 1.0000x reference)
//
#include <hip/hip_runtime.h>

#define B_ 256
#define S_ 512
#define V_ 50000
#define D_ 256
#define L_ 128
#define NPK 64            // Wb pack blocks inside enc1
#define NSP2 4            // loss blocks per batch row
#define NLB (B_ * NSP2)   // 1024 loss blocks

typedef __attribute__((ext_vector_type(8))) short short8;
typedef __attribute__((ext_vector_type(4))) float floatx4;

// ws layout (float units) — no large intermediates:
// [16..1040)    sqp2[1024] (one exclusive slot per loss2 block)
// [1040..1296)  kl[256]
// [1296..1552)  cnt[256] (int)
// [1552..67088) Q[256][256]
// [67088..83472) Wb (bf16 Wout packed [kk][col][hi][e], 32768 shorts)
#define OFF_SQP 16
#define OFF_KL  (OFF_SQP + NLB)
#define OFF_CNT (OFF_KL + 256)
#define OFF_Q   (OFF_CNT + 256)
#define OFF_WB  (OFF_Q + B_ * D_)

__device__ __forceinline__ unsigned short f2bf(float x) {
    unsigned u = __float_as_uint(x);
    u += 0x7FFFu + ((u >> 16) & 1u);
    return (unsigned short)(u >> 16);
}
__device__ __forceinline__ float bf2f(unsigned short u) {
    return __uint_as_float(((unsigned)u) << 16);
}

// ---- K1: blocks [0,NPK) pack Wb; blocks [NPK, NPK+B_) do enc+latent ----
__global__ __launch_bounds__(256) void enc1(
    const int* __restrict__ vocab, const int* __restrict__ order,
    const int* __restrict__ mask, const float* __restrict__ emb,
    const float* __restrict__ eps, const float* __restrict__ Wm,
    const float* __restrict__ bm, const float* __restrict__ Wv,
    const float* __restrict__ bv, const float* __restrict__ Wlin,
    const float* __restrict__ blin, const float* __restrict__ Wout,
    const float* __restrict__ bout, float* __restrict__ ws) {
    __shared__ __align__(16) char smem[11904];
    const int tid = threadIdx.x;
    if (blockIdx.x < NPK) {
        // Wb short-index = kk*8192 + col*32 + hi*8 + e
        //   value = Wout[(kk*32+hi*8+e)*D + col]
        unsigned short* __restrict__ Wb = (unsigned short*)(ws + OFF_WB);
        const int t = blockIdx.x * 256 + tid;   // 0..16383
        const int idx0 = t * 4;
        const int kk = idx0 >> 13;
        const int col = (idx0 >> 5) & 255;
        const int hi = (idx0 >> 3) & 3;
        const int e0 = idx0 & 7;                // 0 or 4
        const int kbase = kk * 32 + hi * 8 + e0;
        ushort4 h;
        h.x = f2bf(Wout[(size_t)(kbase + 0) * D_ + col]);
        h.y = f2bf(Wout[(size_t)(kbase + 1) * D_ + col]);
        h.z = f2bf(Wout[(size_t)(kbase + 2) * D_ + col]);
        h.w = f2bf(Wout[(size_t)(kbase + 3) * D_ + col]);
        ((ushort4*)Wb)[t] = h;
        return;
    }
    // ============ ENC role (verified): phases 1-3, f32 emb gathers ============
    int* s_id1 = (int*)smem;                    // [512]
    int* s_id2 = s_id1 + S_;                    // [512]
    float4* s_part = (float4*)(smem + 4096);    // [3*64]
    float* s_enc = (float*)(smem + 7168);       // [256]
    float* s_mean = (float*)(smem + 8192);      // [128]
    float* s_lv = (float*)(smem + 8704);        // [128]
    float* s_z = (float*)(smem + 9216);         // [128]
    float* s_mem = (float*)(smem + 9728);       // [256]
    float* s_red = (float*)(smem + 10752);      // [256]
    int* s_cntp = (int*)(smem + 11776);
    const int b = blockIdx.x - NPK;
    if (tid == 0) *s_cntp = 0;
    __syncthreads();
    for (int j = tid; j < S_; j += 256) {
        const int mk = mask[b * S_ + j];
        int id1 = 0, id2 = 0;
        if (mk) {
            id1 = vocab[b * S_ + j];
            if (j == 0) {
                id2 = 1;  // BOS
            } else {
                int oi = order[(size_t)(b * S_ + j) * 6];
                if (oi == -1) oi = 1;
                id2 = mask[b * S_ + oi] ? vocab[b * S_ + oi] : 0;
            }
        }
        s_id1[j] = id1;
        s_id2[j] = id2;
        unsigned long long bal = __ballot(mk != 0);
        if ((tid & 63) == 0) atomicAdd(s_cntp, __popcll(bal));
    }
    __syncthreads();
    const int cnt = *s_cntp;
    const int jg = tid >> 6, d4 = tid & 63;
    const float4* eb4 = (const float4*)emb;
    float4 a = {0.f, 0.f, 0.f, 0.f};
#pragma unroll 4
    for (int j = jg; j < cnt; j += 4) {
        float4 x = eb4[(size_t)s_id1[j] * 64 + d4];
        float4 y = eb4[(size_t)s_id2[j] * 64 + d4];
        a.x += x.x + y.x; a.y += x.y + y.y;
        a.z += x.z + y.z; a.w += x.w + y.w;
    }
    if (jg) s_part[(jg - 1) * 64 + d4] = a;
    __syncthreads();
    if (jg == 0) {
#pragma unroll
        for (int g = 0; g < 3; ++g) {
            float4 p = s_part[g * 64 + d4];
            a.x += p.x; a.y += p.y; a.z += p.z; a.w += p.w;
        }
        const float inv = 1.f / fmaxf((float)cnt, 1.f);
        a.x *= inv; a.y *= inv; a.z *= inv; a.w *= inv;
        ((float4*)s_enc)[d4] = a;
    }
    __syncthreads();
    {
        const int l = tid & (L_ - 1);
        const float* W = (tid < L_) ? Wm : Wv;
        const float* bb = (tid < L_) ? bm : bv;
        float dot = bb[l];
        for (int d = 0; d < D_; ++d) dot = fmaf(s_enc[d], W[d * L_ + l], dot);
        if (tid < L_) s_mean[l] = dot; else s_lv[l] = dot;
    }
    __syncthreads();
    float klp = 0.f;
    if (tid < L_) {
        float mn = s_mean[tid], lv = s_lv[tid];
        s_z[tid] = mn + eps[b * L_ + tid] * expf(0.5f * lv);
        klp = 1.f + lv - mn * mn - expf(lv);
    }
    s_red[tid] = klp;
    __syncthreads();
    for (int s = 128; s > 0; s >>= 1) {
        if (tid < s) s_red[tid] += s_red[tid + s];
        __syncthreads();
    }
    if (tid == 0) {
        ws[OFF_KL + b] = s_red[0];
        ((int*)ws)[OFF_CNT + b] = cnt;
    }
    {
        float mem = blin[tid];
        for (int l2 = 0; l2 < L_; ++l2) mem = fmaf(s_z[l2], Wlin[l2 * D_ + tid], mem);
        s_mem[tid] = mem;
    }
    __syncthreads();
    {
        float qv = bout[tid];
        for (int k = 0; k < D_; ++k) qv = fmaf(s_mem[k], Wout[k * D_ + tid], qv);
        ws[OFF_Q + b * D_ + tid] = qv;
    }
}

// ---- K2: direct fused loss; T loaded once, A derived from T (rows share) ----
__global__ __launch_bounds__(256, 2) void loss2(const int* __restrict__ vocab,
                                                const float* __restrict__ emb,
                                                float* __restrict__ ws) {
    __shared__ __align__(16) char smemA[8192];      // A-tile bf16, swizzled
    __shared__ __align__(16) float smemT[16 * 260]; // tgt tile f32, row-padded
    __shared__ int s_tgt[16];
    __shared__ float s_w[16];
    __shared__ int s_inp0;
    __shared__ float s_q[256];
    __shared__ float s_wred[4];
    const int tid = threadIdx.x;
    const int b = blockIdx.x >> 2, part = blockIdx.x & 3;
    const int lane = tid & 63, wv = tid >> 6;
    const int lo = lane & 15, hi = lane >> 4;
    const unsigned short* __restrict__ Wb = (const unsigned short*)(ws + OFF_WB);
    const int cnt = ((const int*)ws)[OFF_CNT + b];
    const int ntiles = (cnt + 16) >> 4;             // ceil((cnt+1)/16)
    s_q[tid] = ws[OFF_Q + b * D_ + tid];
    // B fragments: 32 coalesced 16B loads (Wb L2-hot)
    short8 bfr[4][8];
#pragma unroll
    for (int nt = 0; nt < 4; ++nt)
#pragma unroll
        for (int kk = 0; kk < 8; ++kk)
            bfr[nt][kk] = *(const short8*)(Wb + kk * 8192 +
                                           (wv * 64 + nt * 16 + lo) * 32 + hi * 8);
    float sqacc = 0.f;
    for (int ti = part; ti < ntiles; ti += NSP2) {
        if (tid < 16) {
            const int j = ti * 16 + tid;
            s_tgt[tid] = (j < cnt) ? vocab[b * S_ + j] : ((cnt < S_) ? 2 : 1);
            s_w[tid] = (j <= cnt) ? 1.f : 0.f;
            if (tid == 0) s_inp0 = (ti == 0) ? 1 : vocab[b * S_ + ti * 16 - 1];
        }
        __syncthreads();
        // stage T (f32 padded); derive A rows 1..15 from the same registers
        // (inp[u] = vocab[j-1] = tgt[u-1] within the tile — one global read/row)
#pragma unroll
        for (int i = 0; i < 4; ++i) {
            const int fi = i * 256 + tid;       // float4 index in 16x64 grid
            const int row = fi >> 6, cf4 = fi & 63;
            float4 t = *((const float4*)(emb + (size_t)s_tgt[row] * D_) + cf4);
            *(float4*)(&smemT[row * 260 + cf4 * 4]) = t;
            if (row < 15) {
                const int arow = row + 1;
                ushort4 h;
                h.x = f2bf(t.x); h.y = f2bf(t.y); h.z = f2bf(t.z); h.w = f2bf(t.w);
                const int byt = (arow * 512 + cf4 * 8) ^ ((arow & 7) << 4);
                *(ushort4*)(smemA + byt) = h;
            }
        }
        // A row 0: emb[inp0] (BOS or vocab[ti*16-1])
        if (tid < 64) {
            float4 v = *((const float4*)(emb + (size_t)s_inp0 * D_) + tid);
            ushort4 h;
            h.x = f2bf(v.x); h.y = f2bf(v.y); h.z = f2bf(v.z); h.w = f2bf(v.w);
            *(ushort4*)(smemA + tid * 8) = h;   // row 0: swizzle XOR = 0
        }
        __syncthreads();
        floatx4 acc[4];
#pragma unroll
        for (int nt = 0; nt < 4; ++nt) acc[nt] = (floatx4){0.f, 0.f, 0.f, 0.f};
#pragma unroll
        for (int kk = 0; kk < 8; ++kk) {
            const int byt = (lo * 512 + hi * 16 + kk * 64) ^ ((lo & 7) << 4);
            short8 av = *(const short8*)(smemA + byt);
#pragma unroll
            for (int nt = 0; nt < 4; ++nt)
                acc[nt] = __builtin_amdgcn_mfma_f32_16x16x32_bf16(
                    av, bfr[nt][kk], acc[nt], 0, 0, 0);
        }
        // fused epilogue: (acc + Q[col] - T[row][col])^2 * w — all LDS reads
#pragma unroll
        for (int nt = 0; nt < 4; ++nt) {
            const int col = wv * 64 + nt * 16 + lo;
            const float qv = s_q[col];
#pragma unroll
            for (int r = 0; r < 4; ++r) {
                const int row = hi * 4 + r;
                const float t = smemT[row * 260 + col];
                const float d = acc[nt][r] + qv - t;
                sqacc = fmaf(s_w[row] * d, d, sqacc);
            }
        }
        __syncthreads();   // all reads of tiles done before next stage
    }
#pragma unroll
    for (int off = 32; off; off >>= 1) sqacc += __shfl_down(sqacc, off, 64);
    if (lane == 0) s_wred[wv] = sqacc;
    __syncthreads();
    if (tid == 0)
        ws[OFF_SQP + blockIdx.x] = s_wred[0] + s_wred[1] + s_wred[2] + s_wred[3];
}

// ---- K3: single-block finalize (reduces 1024 sq partials + kl + cnt) ----
__global__ __launch_bounds__(256) void finalize3(const float* __restrict__ ws,
                                                 float* __restrict__ out) {
    __shared__ float s_red[256];
    const int tid = threadIdx.x;
    float sq = 0.f;
#pragma unroll
    for (int i = 0; i < NSP2; ++i) sq += ws[OFF_SQP + i * 256 + tid];
    s_red[tid] = sq;
    __syncthreads();
    for (int s = 128; s > 0; s >>= 1) {
        if (tid < s) s_red[tid] += s_red[tid + s];
        __syncthreads();
    }
    const float sq_tot = s_red[0];
    __syncthreads();
    s_red[tid] = ws[OFF_KL + tid];
    __syncthreads();
    for (int s = 128; s > 0; s >>= 1) {
        if (tid < s) s_red[tid] += s_red[tid + s];
        __syncthreads();
    }
    const float kl_tot = s_red[0];
    __syncthreads();
    s_red[tid] = (float)(((const int*)ws)[OFF_CNT + tid] + 1);
    __syncthreads();
    for (int s = 128; s > 0; s >>= 1) {
        if (tid < s) s_red[tid] += s_red[tid + s];
        __syncthreads();
    }
    if (tid == 0) {
        float denom = s_red[0] * (float)D_;
        if (denom < 1.f) denom = 1.f;
        out[0] = sq_tot / denom;
        out[1] = -0.5f * kl_tot / (float)B_;
    }
}

extern "C" void kernel_launch(void* const* d_in, const int* in_sizes, int n_in,
                              void* d_out, int out_size, void* d_ws, size_t ws_size,
                              hipStream_t stream) {
    const int* vocab = (const int*)d_in[0];
    const int* order = (const int*)d_in[1];
    const int* mask  = (const int*)d_in[2];
    const float* eps  = (const float*)d_in[3];
    const float* emb  = (const float*)d_in[4];
    const float* Wm   = (const float*)d_in[5];
    const float* bm   = (const float*)d_in[6];
    const float* Wv   = (const float*)d_in[7];
    const float* bv   = (const float*)d_in[8];
    const float* Wlin = (const float*)d_in[9];
    const float* blin = (const float*)d_in[10];
    const float* Wout = (const float*)d_in[11];
    const float* bout = (const float*)d_in[12];

    float* ws = (float*)d_ws;
    enc1<<<NPK + B_, 256, 0, stream>>>(vocab, order, mask, emb, eps, Wm, bm,
                                       Wv, bv, Wlin, blin, Wout, bout, ws);
    loss2<<<NLB, 256, 0, stream>>>(vocab, emb, ws);
    finalize3<<<1, 256, 0, stream>>>(ws, (float*)d_out);
}

// Round 13
// 162.114 us; speedup vs baseline: 1.1220x; 1.1220x over previous
//
#include <hip/hip_runtime.h>

#define B_ 256
#define S_ 512
#define V_ 50000
#define D_ 256
#define L_ 128
#define NPK 64            // Wb pack blocks inside enc1
#define NSP2 4            // loss parts per batch row
#define NLB (B_ * NSP2)   // 1024 loss blocks

typedef __attribute__((ext_vector_type(8))) short short8;
typedef __attribute__((ext_vector_type(4))) float floatx4;

// ws layout (float units) — no large intermediates:
// [16..1040)    sqp2[1024] (one exclusive slot per loss2 block)
// [1040..1296)  kl[256]
// [1296..1552)  cnt[256] (int)
// [1552..67088) Q[256][256]
// [67088..83472) Wb (bf16 Wout packed [kk][col][hi][e], 32768 shorts)
#define OFF_SQP 16
#define OFF_KL  (OFF_SQP + NLB)
#define OFF_CNT (OFF_KL + 256)
#define OFF_Q   (OFF_CNT + 256)
#define OFF_WB  (OFF_Q + B_ * D_)

__device__ __forceinline__ unsigned short f2bf(float x) {
    unsigned u = __float_as_uint(x);
    u += 0x7FFFu + ((u >> 16) & 1u);
    return (unsigned short)(u >> 16);
}
__device__ __forceinline__ float bf2f(unsigned short u) {
    return __uint_as_float(((unsigned)u) << 16);
}

// ---- K1: blocks [0,NPK) pack Wb; blocks [NPK, NPK+B_) do enc+latent ----
__global__ __launch_bounds__(256) void enc1(
    const int* __restrict__ vocab, const int* __restrict__ order,
    const int* __restrict__ mask, const float* __restrict__ emb,
    const float* __restrict__ eps, const float* __restrict__ Wm,
    const float* __restrict__ bm, const float* __restrict__ Wv,
    const float* __restrict__ bv, const float* __restrict__ Wlin,
    const float* __restrict__ blin, const float* __restrict__ Wout,
    const float* __restrict__ bout, float* __restrict__ ws) {
    __shared__ __align__(16) char smem[11904];
    const int tid = threadIdx.x;
    if (blockIdx.x < NPK) {
        unsigned short* __restrict__ Wb = (unsigned short*)(ws + OFF_WB);
        const int t = blockIdx.x * 256 + tid;   // 0..16383
        const int idx0 = t * 4;
        const int kk = idx0 >> 13;
        const int col = (idx0 >> 5) & 255;
        const int hi = (idx0 >> 3) & 3;
        const int e0 = idx0 & 7;                // 0 or 4
        const int kbase = kk * 32 + hi * 8 + e0;
        ushort4 h;
        h.x = f2bf(Wout[(size_t)(kbase + 0) * D_ + col]);
        h.y = f2bf(Wout[(size_t)(kbase + 1) * D_ + col]);
        h.z = f2bf(Wout[(size_t)(kbase + 2) * D_ + col]);
        h.w = f2bf(Wout[(size_t)(kbase + 3) * D_ + col]);
        ((ushort4*)Wb)[t] = h;
        return;
    }
    int* s_id1 = (int*)smem;                    // [512]
    int* s_id2 = s_id1 + S_;                    // [512]
    float4* s_part = (float4*)(smem + 4096);    // [3*64]
    float* s_enc = (float*)(smem + 7168);       // [256]
    float* s_mean = (float*)(smem + 8192);      // [128]
    float* s_lv = (float*)(smem + 8704);        // [128]
    float* s_z = (float*)(smem + 9216);         // [128]
    float* s_mem = (float*)(smem + 9728);       // [256]
    float* s_red = (float*)(smem + 10752);      // [256]
    int* s_cntp = (int*)(smem + 11776);
    const int b = blockIdx.x - NPK;
    if (tid == 0) *s_cntp = 0;
    __syncthreads();
    for (int j = tid; j < S_; j += 256) {
        const int mk = mask[b * S_ + j];
        int id1 = 0, id2 = 0;
        if (mk) {
            id1 = vocab[b * S_ + j];
            if (j == 0) {
                id2 = 1;  // BOS
            } else {
                int oi = order[(size_t)(b * S_ + j) * 6];
                if (oi == -1) oi = 1;
                id2 = mask[b * S_ + oi] ? vocab[b * S_ + oi] : 0;
            }
        }
        s_id1[j] = id1;
        s_id2[j] = id2;
        unsigned long long bal = __ballot(mk != 0);
        if ((tid & 63) == 0) atomicAdd(s_cntp, __popcll(bal));
    }
    __syncthreads();
    const int cnt = *s_cntp;
    const int jg = tid >> 6, d4 = tid & 63;
    const float4* eb4 = (const float4*)emb;
    float4 a = {0.f, 0.f, 0.f, 0.f};
#pragma unroll 4
    for (int j = jg; j < cnt; j += 4) {
        float4 x = eb4[(size_t)s_id1[j] * 64 + d4];
        float4 y = eb4[(size_t)s_id2[j] * 64 + d4];
        a.x += x.x + y.x; a.y += x.y + y.y;
        a.z += x.z + y.z; a.w += x.w + y.w;
    }
    if (jg) s_part[(jg - 1) * 64 + d4] = a;
    __syncthreads();
    if (jg == 0) {
#pragma unroll
        for (int g = 0; g < 3; ++g) {
            float4 p = s_part[g * 64 + d4];
            a.x += p.x; a.y += p.y; a.z += p.z; a.w += p.w;
        }
        const float inv = 1.f / fmaxf((float)cnt, 1.f);
        a.x *= inv; a.y *= inv; a.z *= inv; a.w *= inv;
        ((float4*)s_enc)[d4] = a;
    }
    __syncthreads();
    {
        const int l = tid & (L_ - 1);
        const float* W = (tid < L_) ? Wm : Wv;
        const float* bb = (tid < L_) ? bm : bv;
        float dot = bb[l];
        for (int d = 0; d < D_; ++d) dot = fmaf(s_enc[d], W[d * L_ + l], dot);
        if (tid < L_) s_mean[l] = dot; else s_lv[l] = dot;
    }
    __syncthreads();
    float klp = 0.f;
    if (tid < L_) {
        float mn = s_mean[tid], lv = s_lv[tid];
        s_z[tid] = mn + eps[b * L_ + tid] * expf(0.5f * lv);
        klp = 1.f + lv - mn * mn - expf(lv);
    }
    s_red[tid] = klp;
    __syncthreads();
    for (int s = 128; s > 0; s >>= 1) {
        if (tid < s) s_red[tid] += s_red[tid + s];
        __syncthreads();
    }
    if (tid == 0) {
        ws[OFF_KL + b] = s_red[0];
        ((int*)ws)[OFF_CNT + b] = cnt;
    }
    {
        float mem = blin[tid];
        for (int l2 = 0; l2 < L_; ++l2) mem = fmaf(s_z[l2], Wlin[l2 * D_ + tid], mem);
        s_mem[tid] = mem;
    }
    __syncthreads();
    {
        float qv = bout[tid];
        for (int k = 0; k < D_; ++k) qv = fmaf(s_mem[k], Wout[k * D_ + tid], qv);
        ws[OFF_Q + b * D_ + tid] = qv;
    }
}

// ---- K2: fused loss, software-pipelined tiles; ids staged once per block ----
__global__ __launch_bounds__(256, 2) void loss2(const int* __restrict__ vocab,
                                                const float* __restrict__ emb,
                                                float* __restrict__ ws) {
    __shared__ __align__(16) char smemA[8192];      // A-tile bf16, swizzled
    __shared__ __align__(16) float smemT[16 * 260]; // tgt tile f32, row-padded
    __shared__ int s_sid[160];
    __shared__ float s_q[256];
    __shared__ float s_wred[4];
    const int tid = threadIdx.x;
    const int b = blockIdx.x & (B_ - 1), part = blockIdx.x >> 8;  // interleaved
    const int lane = tid & 63, wv = tid >> 6;
    const int lo = lane & 15, hi = lane >> 4;
    const unsigned short* __restrict__ Wb = (const unsigned short*)(ws + OFF_WB);
    const int cnt = ((const int*)ws)[OFF_CNT + b];
    const int ntiles = (cnt + 16) >> 4;             // ceil((cnt+1)/16)
    const int per16 = (ntiles + NSP2 - 1) / NSP2;   // contiguous tiles per part
    const int tb = part * per16;
    const int te = min(tb + per16, ntiles);
    if (tb >= te) {                                 // empty part: still write slot
        if (tid == 0) ws[OFF_SQP + blockIdx.x] = 0.f;
        return;
    }
    const int ecode = (cnt < S_) ? 2 : 1;           // tgt at j==cnt
    const int jlo = (tb > 0) ? tb * 16 - 1 : 0;
    const int jhi = min(te * 16, cnt);              // ids [jlo, jhi), len <= 145
    const int len = jhi - jlo;
    if (tid < len) s_sid[tid] = vocab[b * S_ + jlo + tid];
    s_q[tid] = ws[OFF_Q + b * D_ + tid];
    // B fragments: 32 coalesced 16B loads (Wb L2-hot)
    short8 bfr[4][8];
#pragma unroll
    for (int nt = 0; nt < 4; ++nt)
#pragma unroll
        for (int kk = 0; kk < 8; ++kk)
            bfr[nt][kk] = *(const short8*)(Wb + kk * 8192 +
                                           (wv * 64 + nt * 16 + lo) * 32 + hi * 8);
    __syncthreads();   // s_sid visible before computing gather addresses
    // per-thread staging coords: 4 (row, cf4) pairs; one wave covers one row
    const int srow = tid >> 6;                      // rows srow, srow+4, +8, +12
    const int scf4 = tid & 63;
    // ---- prologue: preload tile tb into registers ----
    float4 RT[4];
    float4 RA0 = {0.f, 0.f, 0.f, 0.f};
#pragma unroll
    for (int i = 0; i < 4; ++i) {
        const int row = srow + i * 4;
        const int j = tb * 16 + row;
        const int id = (j < cnt) ? s_sid[j - jlo] : ecode;
        RT[i] = *((const float4*)(emb + (size_t)id * D_) + scf4);
    }
    if (tid < 64) {
        const int j0 = tb * 16;
        const int aid = (j0 == 0) ? 1 : s_sid[j0 - 1 - jlo];
        RA0 = *((const float4*)(emb + (size_t)aid * D_) + tid);
    }
    float sqacc = 0.f;
    for (int t = tb; t < te; ++t) {
        __syncthreads();   // prev tile's LDS reads complete
        // store staged regs: T (f32 padded) + A rows 1..15 (bf16 swizzled) + A row 0
#pragma unroll
        for (int i = 0; i < 4; ++i) {
            const int row = srow + i * 4;
            *(float4*)(&smemT[row * 260 + scf4 * 4]) = RT[i];
            if (row < 15) {
                const int arow = row + 1;
                ushort4 h;
                h.x = f2bf(RT[i].x); h.y = f2bf(RT[i].y);
                h.z = f2bf(RT[i].z); h.w = f2bf(RT[i].w);
                const int byt = (arow * 512 + scf4 * 8) ^ ((arow & 7) << 4);
                *(ushort4*)(smemA + byt) = h;
            }
        }
        if (tid < 64) {
            ushort4 h;
            h.x = f2bf(RA0.x); h.y = f2bf(RA0.y);
            h.z = f2bf(RA0.z); h.w = f2bf(RA0.w);
            *(ushort4*)(smemA + tid * 8) = h;   // row 0: swizzle XOR = 0
        }
        __syncthreads();   // tiles visible
        // ---- prefetch t+1 into regs (latency hides under MFMA + epilogue) ----
        float4 RTn[4] = {RT[0], RT[1], RT[2], RT[3]};
        float4 RA0n = RA0;
        if (t + 1 < te) {
#pragma unroll
            for (int i = 0; i < 4; ++i) {
                const int row = srow + i * 4;
                const int j = (t + 1) * 16 + row;
                const int id = (j < cnt) ? s_sid[j - jlo] : ecode;
                RTn[i] = *((const float4*)(emb + (size_t)id * D_) + scf4);
            }
            if (tid < 64) {
                const int aid = s_sid[(t + 1) * 16 - 1 - jlo];
                RA0n = *((const float4*)(emb + (size_t)aid * D_) + tid);
            }
        }
        // ---- MFMA ----
        floatx4 acc[4];
#pragma unroll
        for (int nt = 0; nt < 4; ++nt) acc[nt] = (floatx4){0.f, 0.f, 0.f, 0.f};
#pragma unroll
        for (int kk = 0; kk < 8; ++kk) {
            const int byt = (lo * 512 + hi * 16 + kk * 64) ^ ((lo & 7) << 4);
            short8 av = *(const short8*)(smemA + byt);
#pragma unroll
            for (int nt = 0; nt < 4; ++nt)
                acc[nt] = __builtin_amdgcn_mfma_f32_16x16x32_bf16(
                    av, bfr[nt][kk], acc[nt], 0, 0, 0);
        }
        // ---- fused epilogue: (acc + Q[col] - T[row][col])^2 * w, LDS reads ----
#pragma unroll
        for (int nt = 0; nt < 4; ++nt) {
            const int col = wv * 64 + nt * 16 + lo;
            const float qv = s_q[col];
#pragma unroll
            for (int r = 0; r < 4; ++r) {
                const int row = hi * 4 + r;
                const float w = (t * 16 + row <= cnt) ? 1.f : 0.f;
                const float tv = smemT[row * 260 + col];
                const float d = acc[nt][r] + qv - tv;
                sqacc = fmaf(w * d, d, sqacc);
            }
        }
#pragma unroll
        for (int i = 0; i < 4; ++i) RT[i] = RTn[i];
        RA0 = RA0n;
    }
#pragma unroll
    for (int off = 32; off; off >>= 1) sqacc += __shfl_down(sqacc, off, 64);
    if (lane == 0) s_wred[wv] = sqacc;
    __syncthreads();
    if (tid == 0)
        ws[OFF_SQP + blockIdx.x] = s_wred[0] + s_wred[1] + s_wred[2] + s_wred[3];
}

// ---- K3: single-block finalize (reduces 1024 sq partials + kl + cnt) ----
__global__ __launch_bounds__(256) void finalize3(const float* __restrict__ ws,
                                                 float* __restrict__ out) {
    __shared__ float s_red[256];
    const int tid = threadIdx.x;
    float sq = 0.f;
#pragma unroll
    for (int i = 0; i < NSP2; ++i) sq += ws[OFF_SQP + i * 256 + tid];
    s_red[tid] = sq;
    __syncthreads();
    for (int s = 128; s > 0; s >>= 1) {
        if (tid < s) s_red[tid] += s_red[tid + s];
        __syncthreads();
    }
    const float sq_tot = s_red[0];
    __syncthreads();
    s_red[tid] = ws[OFF_KL + tid];
    __syncthreads();
    for (int s = 128; s > 0; s >>= 1) {
        if (tid < s) s_red[tid] += s_red[tid + s];
        __syncthreads();
    }
    const float kl_tot = s_red[0];
    __syncthreads();
    s_red[tid] = (float)(((const int*)ws)[OFF_CNT + tid] + 1);
    __syncthreads();
    for (int s = 128; s > 0; s >>= 1) {
        if (tid < s) s_red[tid] += s_red[tid + s];
        __syncthreads();
    }
    if (tid == 0) {
        float denom = s_red[0] * (float)D_;
        if (denom < 1.f) denom = 1.f;
        out[0] = sq_tot / denom;
        out[1] = -0.5f * kl_tot / (float)B_;
    }
}

extern "C" void kernel_launch(void* const* d_in, const int* in_sizes, int n_in,
                              void* d_out, int out_size, void* d_ws, size_t ws_size,
                              hipStream_t stream) {
    const int* vocab = (const int*)d_in[0];
    const int* order = (const int*)d_in[1];
    const int* mask  = (const int*)d_in[2];
    const float* eps  = (const float*)d_in[3];
    const float* emb  = (const float*)d_in[4];
    const float* Wm   = (const float*)d_in[5];
    const float* bm   = (const float*)d_in[6];
    const float* Wv   = (const float*)d_in[7];
    const float* bv   = (const float*)d_in[8];
    const float* Wlin = (const float*)d_in[9];
    const float* blin = (const float*)d_in[10];
    const float* Wout = (const float*)d_in[11];
    const float* bout = (const float*)d_in[12];

    float* ws = (float*)d_ws;
    enc1<<<NPK + B_, 256, 0, stream>>>(vocab, order, mask, emb, eps, Wm, bm,
                                       Wv, bv, Wlin, blin, Wout, bout, ws);
    loss2<<<NLB, 256, 0, stream>>>(vocab, emb, ws);
    finalize3<<<1, 256, 0, stream>>>(ws, (float*)d_out);
}